// Round 9
// baseline (250.629 us; speedup 1.0000x reference)
//
#include <hip/hip_runtime.h>

#define N_NODES 100000
#define N_EDGES 1600000
#define F_IN    128
#define HID     128
#define F_OUT   64

#define NBUCK   196        // buckets of 512 nodes: dst>>9
#define NCHB    256        // chunk blocks for bucket hist/scatter
#define CHUNK_E (N_EDGES / NCHB)   // 6250 exactly
#define GHN     (NBUCK * NCHB)     // 50176 ghist entries

#define XB_BLKS (N_NODES * 16 / 256)                  // 6250 (exact)
#define WC_BLKS ((HID * F_IN + F_OUT * HID + 255) / 256)  // 96

typedef __attribute__((ext_vector_type(8))) short bf16x8;
typedef __attribute__((ext_vector_type(4))) float f32x4;

// ---------------- bf16 helpers ----------------

__device__ __forceinline__ unsigned int bf16rn(float f) {
    unsigned int u = __float_as_uint(f);
    return (u + 0x7fffu + ((u >> 16) & 1u)) >> 16;
}
__device__ __forceinline__ float bf16tof(unsigned short h) {
    return __uint_as_float(((unsigned int)h) << 16);
}

// ---------------- pre: xh convert + weight transpose + bucket histogram ----------------

__global__ __launch_bounds__(256) void k_pre(
        const float* __restrict__ x, unsigned short* __restrict__ xh,
        const float* __restrict__ W1, const float* __restrict__ W2,
        unsigned short* __restrict__ w1t, unsigned short* __restrict__ w2t,
        const int* __restrict__ dst, int* __restrict__ ghist) {
    __shared__ int bins[NBUCK];
    const int blk = blockIdx.x;
    const int t = threadIdx.x;
    if (blk < XB_BLKS) {
        int i = blk * 256 + t;
        float4 a = ((const float4*)x)[2 * i];
        float4 b = ((const float4*)x)[2 * i + 1];
        uint4 r;
        r.x = bf16rn(a.x) | (bf16rn(a.y) << 16);
        r.y = bf16rn(a.z) | (bf16rn(a.w) << 16);
        r.z = bf16rn(b.x) | (bf16rn(b.y) << 16);
        r.w = bf16rn(b.z) | (bf16rn(b.w) << 16);
        ((uint4*)xh)[i] = r;
    } else if (blk < XB_BLKS + WC_BLKS) {
        int i = (blk - XB_BLKS) * 256 + t;
        if (i < HID * F_IN) {
            int n = i >> 7, k = i & 127;
            w1t[i] = (unsigned short)bf16rn(W1[k * HID + n]);
        }
        int j = i - HID * F_IN;
        if (j >= 0 && j < F_OUT * HID) {
            int n = j >> 7, k = j & 127;
            w2t[j] = (unsigned short)bf16rn(W2[k * F_OUT + n]);
        }
    } else {
        int cb = blk - XB_BLKS - WC_BLKS;
        for (int j = t; j < NBUCK; j += 256) bins[j] = 0;
        __syncthreads();
        const int base = cb * CHUNK_E;
        for (int i = t; i < CHUNK_E; i += 256)
            atomicAdd(&bins[dst[base + i] >> 9], 1);
        __syncthreads();
        for (int j = t; j < NBUCK; j += 256)
            ghist[j * NCHB + cb] = bins[j];       // bucket-major
    }
}

// ---------------- generalized hierarchical exclusive scan (in-place) ----------------

__global__ void k_scan_part(const int* __restrict__ data, int* __restrict__ part, int n) {
    int i = blockIdx.x * 256 + threadIdx.x;
    int v = (i < n) ? data[i] : 0;
    #pragma unroll
    for (int off = 32; off > 0; off >>= 1) v += __shfl_down(v, off, 64);
    __shared__ int ws[4];
    if ((threadIdx.x & 63) == 0) ws[threadIdx.x >> 6] = v;
    __syncthreads();
    if (threadIdx.x == 0) part[blockIdx.x] = ws[0] + ws[1] + ws[2] + ws[3];
}

__global__ __launch_bounds__(512) void k_scan_top(int* __restrict__ part, int nparts) {
    __shared__ int s[512];
    int t = threadIdx.x;
    int v = (t < nparts) ? part[t] : 0;
    s[t] = v;
    __syncthreads();
    for (int off = 1; off < 512; off <<= 1) {
        int u = (t >= off) ? s[t - off] : 0;
        __syncthreads();
        s[t] += u;
        __syncthreads();
    }
    if (t < nparts) part[t] = s[t] - v;           // exclusive
}

__global__ void k_scan_down(int* __restrict__ data, const int* __restrict__ part, int n) {
    __shared__ int s[256];
    int t = threadIdx.x;
    int i = blockIdx.x * 256 + t;
    int v = (i < n) ? data[i] : 0;
    s[t] = v;
    __syncthreads();
    for (int off = 1; off < 256; off <<= 1) {
        int u = (t >= off) ? s[t - off] : 0;
        __syncthreads();
        s[t] += u;
        __syncthreads();
    }
    if (i < n) data[i] = part[blockIdx.x] + s[t] - v;   // exclusive, in place
}

// ---------------- bucket scatter: LDS cursors, dlocal packed into bits 17..25 ----------------

__global__ __launch_bounds__(256) void k_bscatter(const int* __restrict__ src,
                                                  const int* __restrict__ dst,
                                                  const float* __restrict__ w,
                                                  const int* __restrict__ ghist,  // scanned
                                                  int2* __restrict__ spw) {
    __shared__ int cur[NBUCK];
    const int t = threadIdx.x;
    const int blk = blockIdx.x;
    for (int j = t; j < NBUCK; j += 256) cur[j] = ghist[j * NCHB + blk];
    __syncthreads();
    const int base = blk * CHUNK_E;
    for (int i = t; i < CHUNK_E; i += 256) {
        int e = base + i;
        int d = dst[e];
        int b = d >> 9;
        int pos = atomicAdd(&cur[b], 1);
        int2 p;
        p.x = src[e] | ((d & 511) << 17);     // src < 2^17
        p.y = __float_as_int(w[e]);
        spw[pos] = p;
    }
}

// ---------------- per-bucket CSR finalize: row_ptr, dinv, pairs ----------------

__global__ __launch_bounds__(512) void k_csr(const int2* __restrict__ spw,
                                             const int* __restrict__ ghist,   // scanned
                                             int* __restrict__ row_ptr,
                                             float* __restrict__ dinv,
                                             int2* __restrict__ pairs) {
    __shared__ int   scnt[512];
    __shared__ float swsum[512];
    __shared__ int   sexcl[512];
    const int t = threadIdx.x;
    const int b = blockIdx.x;
    const int bstart = ghist[b * NCHB];
    const int bend   = (b == NBUCK - 1) ? N_EDGES : ghist[(b + 1) * NCHB];
    const int ne = bend - bstart;

    scnt[t] = 0; swsum[t] = 0.0f;
    __syncthreads();
    for (int i = t; i < ne; i += 512) {
        int2 pe = spw[bstart + i];
        int dl = pe.x >> 17;
        atomicAdd(&scnt[dl], 1);
        atomicAdd(&swsum[dl], __int_as_float(pe.y));
    }
    __syncthreads();

    sexcl[t] = scnt[t];
    __syncthreads();
    for (int off = 1; off < 512; off <<= 1) {
        int u = (t >= off) ? sexcl[t - off] : 0;
        __syncthreads();
        sexcl[t] += u;
        __syncthreads();
    }
    int excl = sexcl[t] - scnt[t];

    int node = b * 512 + t;
    if (node < N_NODES) {
        row_ptr[node] = bstart + excl;
        dinv[node] = rsqrtf(1.0f + swsum[t]);
    }
    if (b == NBUCK - 1 && t == 0) row_ptr[N_NODES] = N_EDGES;

    sexcl[t] = excl;
    __syncthreads();
    scnt[t] = 0;
    __syncthreads();

    for (int i = t; i < ne; i += 512) {
        int2 pe = spw[bstart + i];
        int dl = pe.x >> 17;
        int r = atomicAdd(&scnt[dl], 1);
        int2 q;
        q.x = pe.x & 0x1FFFF;
        q.y = pe.y;
        pairs[bstart + sexcl[dl] + r] = q;
    }
}

// ---------------- fused gather + 2-layer MFMA MLP (edge-balanced) ----------------
// Block = 512 threads = 16 nodes. Phase A: the block's contiguous edge range is
// split EVENLY across the 16 lane-groups (segmented reduction; LDS fp32 tile,
// ds_add_f32 flush at row boundaries only). Phase B/C: MFMA as before.

__global__ __launch_bounds__(512) void k_gmlp(
        const int2* __restrict__ pairs,
        const int* __restrict__ row_ptr,
        const float* __restrict__ dinv,
        const unsigned short* __restrict__ xh,
        const unsigned short* __restrict__ w1t,   // [128][128] bf16, w1t[n][k]
        const float* __restrict__ b1,
        const unsigned short* __restrict__ w2t,   // [64][128] bf16, w2t[n][k]
        const float* __restrict__ b2,
        float* __restrict__ out) {
    __shared__ float at[16][128];            // fp32 accumulation tile (8 KB)
    __shared__ unsigned short gt[16][128];   // gathered ax tile bf16 (swizzled)
    __shared__ unsigned short ht[16][128];   // relu(h) tile bf16 (swizzled)
    __shared__ int rp[17];

    const int t = threadIdx.x;
    const int row0 = blockIdx.x * 16;
    const int grp  = t >> 5;
    const int lane = t & 31;
    const ushort4* xh4 = (const ushort4*)xh;

    if (t < 17) rp[t] = row_ptr[row0 + t];

    // seed with self term: at[grp] = dn * x[row0+grp]
    const int n = row0 + grp;
    const float dn = dinv[n];
    ushort4 sv = xh4[n * 32 + lane];
    at[grp][lane * 4 + 0] = dn * bf16tof(sv.x);
    at[grp][lane * 4 + 1] = dn * bf16tof(sv.y);
    at[grp][lane * 4 + 2] = dn * bf16tof(sv.z);
    at[grp][lane * 4 + 3] = dn * bf16tof(sv.w);
    __syncthreads();

    // ---- phase A: edge-balanced segmented gather ----
    {
        const int ebeg = rp[0], eend = rp[16];
        const int cpg = (eend - ebeg + 15) >> 4;     // edges per group
        int e  = ebeg + grp * cpg;
        int e1 = e + cpg;
        if (e1 > eend) e1 = eend;
        if (e < e1) {
            int row = 0;
            while (rp[row + 1] <= e) ++row;          // locate first row of chunk
            while (e < e1) {
                while (rp[row + 1] <= e) ++row;      // skip finished rows
                int send = rp[row + 1] < e1 ? rp[row + 1] : e1;
                float4 acc = {0.f, 0.f, 0.f, 0.f};
                for (; e + 3 < send; e += 4) {       // 4 independent gathers in flight
                    int2 p0 = pairs[e];
                    int2 p1 = pairs[e + 1];
                    int2 p2 = pairs[e + 2];
                    int2 p3 = pairs[e + 3];
                    float nw0 = dinv[p0.x] * __int_as_float(p0.y);
                    float nw1 = dinv[p1.x] * __int_as_float(p1.y);
                    float nw2 = dinv[p2.x] * __int_as_float(p2.y);
                    float nw3 = dinv[p3.x] * __int_as_float(p3.y);
                    ushort4 v0 = xh4[p0.x * 32 + lane];
                    ushort4 v1 = xh4[p1.x * 32 + lane];
                    ushort4 v2 = xh4[p2.x * 32 + lane];
                    ushort4 v3 = xh4[p3.x * 32 + lane];
                    acc.x += nw0 * bf16tof(v0.x); acc.y += nw0 * bf16tof(v0.y);
                    acc.z += nw0 * bf16tof(v0.z); acc.w += nw0 * bf16tof(v0.w);
                    acc.x += nw1 * bf16tof(v1.x); acc.y += nw1 * bf16tof(v1.y);
                    acc.z += nw1 * bf16tof(v1.z); acc.w += nw1 * bf16tof(v1.w);
                    acc.x += nw2 * bf16tof(v2.x); acc.y += nw2 * bf16tof(v2.y);
                    acc.z += nw2 * bf16tof(v2.z); acc.w += nw2 * bf16tof(v2.w);
                    acc.x += nw3 * bf16tof(v3.x); acc.y += nw3 * bf16tof(v3.y);
                    acc.z += nw3 * bf16tof(v3.z); acc.w += nw3 * bf16tof(v3.w);
                }
                for (; e < send; ++e) {
                    int2 p = pairs[e];
                    float nw = dinv[p.x] * __int_as_float(p.y);
                    ushort4 v = xh4[p.x * 32 + lane];
                    acc.x += nw * bf16tof(v.x); acc.y += nw * bf16tof(v.y);
                    acc.z += nw * bf16tof(v.z); acc.w += nw * bf16tof(v.w);
                }
                atomicAdd(&at[row][lane * 4 + 0], acc.x);   // ds_add_f32
                atomicAdd(&at[row][lane * 4 + 1], acc.y);
                atomicAdd(&at[row][lane * 4 + 2], acc.z);
                atomicAdd(&at[row][lane * 4 + 3], acc.w);
            }
        }
    }
    __syncthreads();

    // finalize: scale by dn, pack bf16 into swizzled gt
    {
        float ax0 = at[grp][lane * 4 + 0] * dn;
        float ax1 = at[grp][lane * 4 + 1] * dn;
        float ax2 = at[grp][lane * 4 + 2] * dn;
        float ax3 = at[grp][lane * 4 + 3] * dn;
        uint2 r;
        r.x = bf16rn(ax0) | (bf16rn(ax1) << 16);
        r.y = bf16rn(ax2) | (bf16rn(ax3) << 16);
        *(uint2*)&gt[grp][(lane * 4) ^ ((grp & 7) << 3)] = r;
    }
    __syncthreads();

    const int wv   = t >> 6;          // wave 0..7
    const int wl   = t & 63;
    const int r16  = wl & 15;
    const int g    = wl >> 4;
    const int swr  = (r16 & 7) << 3;

    // ---- phase B: layer 1, wave wv -> h cols wv*16 .. +15 ----
    {
        bf16x8 a[4];
        #pragma unroll
        for (int kt = 0; kt < 4; ++kt)
            a[kt] = *(const bf16x8*)&gt[r16][(kt * 32 + g * 8) ^ swr];

        f32x4 acc = {0.f, 0.f, 0.f, 0.f};
        const unsigned short* bcol = w1t + (wv * 16 + r16) * HID + g * 8;
        #pragma unroll
        for (int kt = 0; kt < 4; ++kt) {
            bf16x8 b = *(const bf16x8*)(bcol + kt * 32);
            acc = __builtin_amdgcn_mfma_f32_16x16x32_bf16(a[kt], b, acc, 0, 0, 0);
        }
        float bias = b1[wv * 16 + r16];
        #pragma unroll
        for (int q = 0; q < 4; ++q) {
            int row = g * 4 + q;
            float v = fmaxf(acc[q] + bias, 0.0f);
            ht[row][(wv * 16 + r16) ^ ((row & 7) << 3)] = (unsigned short)bf16rn(v);
        }
    }
    __syncthreads();

    // ---- phase C: layer 2, waves 0..3 -> out cols wv*16 .. +15 ----
    if (wv < 4) {
        bf16x8 a2[4];
        #pragma unroll
        for (int kt = 0; kt < 4; ++kt)
            a2[kt] = *(const bf16x8*)&ht[r16][(kt * 32 + g * 8) ^ swr];

        f32x4 acc = {0.f, 0.f, 0.f, 0.f};
        const unsigned short* bcol = w2t + (wv * 16 + r16) * HID + g * 8;
        #pragma unroll
        for (int kt = 0; kt < 4; ++kt) {
            bf16x8 b = *(const bf16x8*)(bcol + kt * 32);
            acc = __builtin_amdgcn_mfma_f32_16x16x32_bf16(a2[kt], b, acc, 0, 0, 0);
        }
        float bias = b2[wv * 16 + r16];
        #pragma unroll
        for (int q = 0; q < 4; ++q)
            out[(size_t)(row0 + g * 4 + q) * F_OUT + wv * 16 + r16] = acc[q] + bias;
    }
}

// ---------------- launch ----------------

extern "C" void kernel_launch(void* const* d_in, const int* in_sizes, int n_in,
                              void* d_out, int out_size, void* d_ws, size_t ws_size,
                              hipStream_t stream) {
    const float* x  = (const float*)d_in[0];
    const int*   ei = (const int*)d_in[1];
    const float* ew = (const float*)d_in[2];
    const float* W1 = (const float*)d_in[3];
    const float* b1 = (const float*)d_in[4];
    const float* W2 = (const float*)d_in[5];
    const float* b2 = (const float*)d_in[6];
    float* out = (float*)d_out;

    const int* src = ei;
    const int* dst = ei + N_EDGES;

    // workspace layout — explicit 16B-aligned carve-out
    char* base = (char*)d_ws;
    auto alloc16 = [&](size_t bytes) { char* p = base; base += (bytes + 15) & ~(size_t)15; return p; };

    float*          dinv    = (float*)         alloc16(N_NODES * 4);
    unsigned short* xh      = (unsigned short*)alloc16((size_t)N_NODES * F_IN * 2);
    int*            row_ptr = (int*)           alloc16((N_NODES + 1) * 4);
    int*            ghist   = (int*)           alloc16(GHN * 4);
    int*            part    = (int*)           alloc16(256 * 4);
    int2*           pairs   = (int2*)          alloc16((size_t)N_EDGES * 8);
    int2*           spw     = (int2*)          alloc16((size_t)N_EDGES * 8);
    unsigned short* w1t     = (unsigned short*)alloc16(HID * F_IN * 2);
    unsigned short* w2t     = (unsigned short*)alloc16(F_OUT * HID * 2);

    const int GH_BLKS = (GHN + 255) / 256;   // 196

    k_pre<<<XB_BLKS + WC_BLKS + NCHB, 256, 0, stream>>>(x, xh, W1, W2, w1t, w2t, dst, ghist);
    k_scan_part<<<GH_BLKS, 256, 0, stream>>>(ghist, part, GHN);
    k_scan_top<<<1, 512, 0, stream>>>(part, GH_BLKS);
    k_scan_down<<<GH_BLKS, 256, 0, stream>>>(ghist, part, GHN);
    k_bscatter<<<NCHB, 256, 0, stream>>>(src, dst, ew, ghist, spw);
    k_csr<<<NBUCK, 512, 0, stream>>>(spw, ghist, row_ptr, dinv, pairs);
    k_gmlp<<<N_NODES / 16, 512, 0, stream>>>(pairs, row_ptr, dinv, xh, w1t, b1, w2t, b2, out);
}

// Round 10
// 187.417 us; speedup vs baseline: 1.3373x; 1.3373x over previous
//
#include <hip/hip_runtime.h>

#define N_NODES 100000
#define N_EDGES 1600000
#define F_IN    128
#define HID     128
#define F_OUT   64

#define NBUCK   196        // buckets of 512 nodes: dst>>9
#define NCHB    256        // chunk blocks for bucket hist/scatter
#define CHUNK_E (N_EDGES / NCHB)   // 6250 exactly
#define GHN     (NBUCK * NCHB)     // 50176 ghist entries

#define XB_BLKS (N_NODES * 16 / 256)                  // 6250 (exact)
#define WC_BLKS ((HID * F_IN + F_OUT * HID + 255) / 256)  // 96

typedef __attribute__((ext_vector_type(8))) short bf16x8;
typedef __attribute__((ext_vector_type(4))) float f32x4;

// ---------------- bf16 helpers ----------------

__device__ __forceinline__ unsigned int bf16rn(float f) {
    unsigned int u = __float_as_uint(f);
    return (u + 0x7fffu + ((u >> 16) & 1u)) >> 16;
}
__device__ __forceinline__ float bf16tof(unsigned short h) {
    return __uint_as_float(((unsigned int)h) << 16);
}

// ---------------- pre: xh convert + weight transpose + bucket histogram ----------------

__global__ __launch_bounds__(256) void k_pre(
        const float* __restrict__ x, unsigned short* __restrict__ xh,
        const float* __restrict__ W1, const float* __restrict__ W2,
        unsigned short* __restrict__ w1t, unsigned short* __restrict__ w2t,
        const int* __restrict__ dst, int* __restrict__ ghist) {
    __shared__ int bins[NBUCK];
    const int blk = blockIdx.x;
    const int t = threadIdx.x;
    if (blk < XB_BLKS) {
        int i = blk * 256 + t;
        float4 a = ((const float4*)x)[2 * i];
        float4 b = ((const float4*)x)[2 * i + 1];
        uint4 r;
        r.x = bf16rn(a.x) | (bf16rn(a.y) << 16);
        r.y = bf16rn(a.z) | (bf16rn(a.w) << 16);
        r.z = bf16rn(b.x) | (bf16rn(b.y) << 16);
        r.w = bf16rn(b.z) | (bf16rn(b.w) << 16);
        ((uint4*)xh)[i] = r;
    } else if (blk < XB_BLKS + WC_BLKS) {
        int i = (blk - XB_BLKS) * 256 + t;
        if (i < HID * F_IN) {
            int n = i >> 7, k = i & 127;
            w1t[i] = (unsigned short)bf16rn(W1[k * HID + n]);
        }
        int j = i - HID * F_IN;
        if (j >= 0 && j < F_OUT * HID) {
            int n = j >> 7, k = j & 127;
            w2t[j] = (unsigned short)bf16rn(W2[k * F_OUT + n]);
        }
    } else {
        int cb = blk - XB_BLKS - WC_BLKS;
        for (int j = t; j < NBUCK; j += 256) bins[j] = 0;
        __syncthreads();
        const int base = cb * CHUNK_E;
        for (int i = t; i < CHUNK_E; i += 256)
            atomicAdd(&bins[dst[base + i] >> 9], 1);
        __syncthreads();
        for (int j = t; j < NBUCK; j += 256)
            ghist[j * NCHB + cb] = bins[j];       // bucket-major
    }
}

// ---------------- generalized hierarchical exclusive scan (in-place) ----------------

__global__ void k_scan_part(const int* __restrict__ data, int* __restrict__ part, int n) {
    int i = blockIdx.x * 256 + threadIdx.x;
    int v = (i < n) ? data[i] : 0;
    #pragma unroll
    for (int off = 32; off > 0; off >>= 1) v += __shfl_down(v, off, 64);
    __shared__ int ws[4];
    if ((threadIdx.x & 63) == 0) ws[threadIdx.x >> 6] = v;
    __syncthreads();
    if (threadIdx.x == 0) part[blockIdx.x] = ws[0] + ws[1] + ws[2] + ws[3];
}

__global__ __launch_bounds__(512) void k_scan_top(int* __restrict__ part, int nparts) {
    __shared__ int s[512];
    int t = threadIdx.x;
    int v = (t < nparts) ? part[t] : 0;
    s[t] = v;
    __syncthreads();
    for (int off = 1; off < 512; off <<= 1) {
        int u = (t >= off) ? s[t - off] : 0;
        __syncthreads();
        s[t] += u;
        __syncthreads();
    }
    if (t < nparts) part[t] = s[t] - v;           // exclusive
}

__global__ void k_scan_down(int* __restrict__ data, const int* __restrict__ part, int n) {
    __shared__ int s[256];
    int t = threadIdx.x;
    int i = blockIdx.x * 256 + t;
    int v = (i < n) ? data[i] : 0;
    s[t] = v;
    __syncthreads();
    for (int off = 1; off < 256; off <<= 1) {
        int u = (t >= off) ? s[t - off] : 0;
        __syncthreads();
        s[t] += u;
        __syncthreads();
    }
    if (i < n) data[i] = part[blockIdx.x] + s[t] - v;   // exclusive, in place
}

// ---------------- bucket scatter: LDS cursors, dlocal packed into bits 17..25 ----------------

__global__ __launch_bounds__(256) void k_bscatter(const int* __restrict__ src,
                                                  const int* __restrict__ dst,
                                                  const float* __restrict__ w,
                                                  const int* __restrict__ ghist,  // scanned
                                                  int2* __restrict__ spw) {
    __shared__ int cur[NBUCK];
    const int t = threadIdx.x;
    const int blk = blockIdx.x;
    for (int j = t; j < NBUCK; j += 256) cur[j] = ghist[j * NCHB + blk];
    __syncthreads();
    const int base = blk * CHUNK_E;
    for (int i = t; i < CHUNK_E; i += 256) {
        int e = base + i;
        int d = dst[e];
        int b = d >> 9;
        int pos = atomicAdd(&cur[b], 1);
        int2 p;
        p.x = src[e] | ((d & 511) << 17);     // src < 2^17
        p.y = __float_as_int(w[e]);
        spw[pos] = p;
    }
}

// ---------------- per-bucket CSR finalize: row_ptr, dinv, pairs ----------------

__global__ __launch_bounds__(512) void k_csr(const int2* __restrict__ spw,
                                             const int* __restrict__ ghist,   // scanned
                                             int* __restrict__ row_ptr,
                                             float* __restrict__ dinv,
                                             int2* __restrict__ pairs) {
    __shared__ int   scnt[512];
    __shared__ float swsum[512];
    __shared__ int   sexcl[512];
    const int t = threadIdx.x;
    const int b = blockIdx.x;
    const int bstart = ghist[b * NCHB];
    const int bend   = (b == NBUCK - 1) ? N_EDGES : ghist[(b + 1) * NCHB];
    const int ne = bend - bstart;

    scnt[t] = 0; swsum[t] = 0.0f;
    __syncthreads();
    for (int i = t; i < ne; i += 512) {
        int2 pe = spw[bstart + i];
        int dl = pe.x >> 17;
        atomicAdd(&scnt[dl], 1);
        atomicAdd(&swsum[dl], __int_as_float(pe.y));
    }
    __syncthreads();

    sexcl[t] = scnt[t];
    __syncthreads();
    for (int off = 1; off < 512; off <<= 1) {
        int u = (t >= off) ? sexcl[t - off] : 0;
        __syncthreads();
        sexcl[t] += u;
        __syncthreads();
    }
    int excl = sexcl[t] - scnt[t];

    int node = b * 512 + t;
    if (node < N_NODES) {
        row_ptr[node] = bstart + excl;
        dinv[node] = rsqrtf(1.0f + swsum[t]);
    }
    if (b == NBUCK - 1 && t == 0) row_ptr[N_NODES] = N_EDGES;

    sexcl[t] = excl;
    __syncthreads();
    scnt[t] = 0;
    __syncthreads();

    for (int i = t; i < ne; i += 512) {
        int2 pe = spw[bstart + i];
        int dl = pe.x >> 17;
        int r = atomicAdd(&scnt[dl], 1);
        int2 q;
        q.x = pe.x & 0x1FFFF;
        q.y = pe.y;
        pairs[bstart + sexcl[dl] + r] = q;
    }
}

// ---------------- gather-aggregate (split, barrier-free; bf16 in/out, fp32 accum) ----------------
// axh[n] = bf16( dinv[n] * ( dinv[n]*xh[n] + sum_e dinv[src]*w * xh[src] ) )

__global__ __launch_bounds__(256) void k_gather(const int2* __restrict__ pairs,
                                                const int* __restrict__ row_ptr,
                                                const float* __restrict__ dinv,
                                                const unsigned short* __restrict__ xh,
                                                unsigned short* __restrict__ axh) {
    int t = blockIdx.x * 256 + threadIdx.x;
    int n = t >> 5;
    int lane = t & 31;
    if (n >= N_NODES) return;

    const ushort4* xh4 = (const ushort4*)xh;
    float dn = dinv[n];
    ushort4 sv = xh4[n * 32 + lane];              // self term (bf16)
    float4 acc;
    acc.x = dn * bf16tof(sv.x);
    acc.y = dn * bf16tof(sv.y);
    acc.z = dn * bf16tof(sv.z);
    acc.w = dn * bf16tof(sv.w);

    int beg = row_ptr[n];
    int end = row_ptr[n + 1];
    int e = beg;
    for (; e + 3 < end; e += 4) {                 // 4 independent gathers in flight
        int2 p0 = pairs[e];
        int2 p1 = pairs[e + 1];
        int2 p2 = pairs[e + 2];
        int2 p3 = pairs[e + 3];
        float nw0 = dinv[p0.x] * __int_as_float(p0.y);
        float nw1 = dinv[p1.x] * __int_as_float(p1.y);
        float nw2 = dinv[p2.x] * __int_as_float(p2.y);
        float nw3 = dinv[p3.x] * __int_as_float(p3.y);
        ushort4 v0 = xh4[p0.x * 32 + lane];
        ushort4 v1 = xh4[p1.x * 32 + lane];
        ushort4 v2 = xh4[p2.x * 32 + lane];
        ushort4 v3 = xh4[p3.x * 32 + lane];
        acc.x += nw0 * bf16tof(v0.x); acc.y += nw0 * bf16tof(v0.y);
        acc.z += nw0 * bf16tof(v0.z); acc.w += nw0 * bf16tof(v0.w);
        acc.x += nw1 * bf16tof(v1.x); acc.y += nw1 * bf16tof(v1.y);
        acc.z += nw1 * bf16tof(v1.z); acc.w += nw1 * bf16tof(v1.w);
        acc.x += nw2 * bf16tof(v2.x); acc.y += nw2 * bf16tof(v2.y);
        acc.z += nw2 * bf16tof(v2.z); acc.w += nw2 * bf16tof(v2.w);
        acc.x += nw3 * bf16tof(v3.x); acc.y += nw3 * bf16tof(v3.y);
        acc.z += nw3 * bf16tof(v3.z); acc.w += nw3 * bf16tof(v3.w);
    }
    for (; e < end; ++e) {
        int2 p = pairs[e];
        float nw = dinv[p.x] * __int_as_float(p.y);
        ushort4 v = xh4[p.x * 32 + lane];
        acc.x += nw * bf16tof(v.x); acc.y += nw * bf16tof(v.y);
        acc.z += nw * bf16tof(v.z); acc.w += nw * bf16tof(v.w);
    }
    acc.x *= dn; acc.y *= dn; acc.z *= dn; acc.w *= dn;
    uint2 r;
    r.x = bf16rn(acc.x) | (bf16rn(acc.y) << 16);
    r.y = bf16rn(acc.z) | (bf16rn(acc.w) << 16);
    ((uint2*)axh)[n * 32 + lane] = r;
}

// ---------------- MFMA MLP: out = relu(axh@W1 + b1) @ W2 + b2 ----------------
// 4 waves/block, 16 rows/wave. 16x16x32 bf16 MFMA, fp32 accum.
// C/D layout (m89-verified): col = lane&15, row = (lane>>4)*4 + reg.
// A/B frag: row(A)/col(B) = lane&15, k = (lane>>4)*8 + i (contiguous 16B).

__global__ __launch_bounds__(256) void k_mlp(
        const unsigned short* __restrict__ axh,   // [N][128] bf16
        const unsigned short* __restrict__ w1t,   // [128][128] bf16, w1t[n][k]
        const float* __restrict__ b1,
        const unsigned short* __restrict__ w2t,   // [64][128] bf16, w2t[n][k]
        const float* __restrict__ b2,
        float* __restrict__ out) {
    __shared__ unsigned short hbuf[4][16][128];   // per-wave h tile, XOR-swizzled

    const int wid  = threadIdx.x >> 6;
    const int lane = threadIdx.x & 63;
    const int r = lane & 15;
    const int g = lane >> 4;

    const int row0 = (blockIdx.x * 4 + wid) * 16;
    const bool valid = (row0 + 16 <= N_NODES);    // N%16==0: waves all-or-nothing
    const int row0s = valid ? row0 : 0;

    bf16x8 a[4];
    const unsigned short* arow = axh + (size_t)(row0s + r) * HID + g * 8;
    #pragma unroll
    for (int kt = 0; kt < 4; ++kt)
        a[kt] = *(const bf16x8*)(arow + kt * 32);

    const int swr = (r & 7) << 3;

    #pragma unroll
    for (int nt = 0; nt < 8; ++nt) {
        f32x4 acc = {0.f, 0.f, 0.f, 0.f};
        const unsigned short* bcol = w1t + (nt * 16 + r) * HID + g * 8;
        #pragma unroll
        for (int kt = 0; kt < 4; ++kt) {
            bf16x8 b = *(const bf16x8*)(bcol + kt * 32);
            acc = __builtin_amdgcn_mfma_f32_16x16x32_bf16(a[kt], b, acc, 0, 0, 0);
        }
        float bias = b1[nt * 16 + r];
        #pragma unroll
        for (int q = 0; q < 4; ++q) {
            int row = g * 4 + q;
            float v = fmaxf(acc[q] + bias, 0.0f);
            hbuf[wid][row][(nt * 16 + r) ^ ((row & 7) << 3)] = (unsigned short)bf16rn(v);
        }
    }
    __syncthreads();   // all waves reach this (no early returns)

    bf16x8 a2[4];
    #pragma unroll
    for (int kt = 0; kt < 4; ++kt)
        a2[kt] = *(const bf16x8*)(&hbuf[wid][r][(kt * 32 + g * 8) ^ swr]);

    #pragma unroll
    for (int nt = 0; nt < 4; ++nt) {
        f32x4 acc = {0.f, 0.f, 0.f, 0.f};
        const unsigned short* bcol = w2t + (nt * 16 + r) * HID + g * 8;
        #pragma unroll
        for (int kt = 0; kt < 4; ++kt) {
            bf16x8 b = *(const bf16x8*)(bcol + kt * 32);
            acc = __builtin_amdgcn_mfma_f32_16x16x32_bf16(a2[kt], b, acc, 0, 0, 0);
        }
        if (valid) {
            float bias = b2[nt * 16 + r];
            #pragma unroll
            for (int q = 0; q < 4; ++q)
                out[(size_t)(row0 + g * 4 + q) * F_OUT + nt * 16 + r] = acc[q] + bias;
        }
    }
}

// ---------------- launch ----------------

extern "C" void kernel_launch(void* const* d_in, const int* in_sizes, int n_in,
                              void* d_out, int out_size, void* d_ws, size_t ws_size,
                              hipStream_t stream) {
    const float* x  = (const float*)d_in[0];
    const int*   ei = (const int*)d_in[1];
    const float* ew = (const float*)d_in[2];
    const float* W1 = (const float*)d_in[3];
    const float* b1 = (const float*)d_in[4];
    const float* W2 = (const float*)d_in[5];
    const float* b2 = (const float*)d_in[6];
    float* out = (float*)d_out;

    const int* src = ei;
    const int* dst = ei + N_EDGES;

    // workspace layout — explicit 16B-aligned carve-out.
    // NOTE: axh aliases spw (spw is dead after k_csr; axh written after).
    char* base = (char*)d_ws;
    auto alloc16 = [&](size_t bytes) { char* p = base; base += (bytes + 15) & ~(size_t)15; return p; };

    float*          dinv    = (float*)         alloc16(N_NODES * 4);
    unsigned short* xh      = (unsigned short*)alloc16((size_t)N_NODES * F_IN * 2);
    int*            row_ptr = (int*)           alloc16((N_NODES + 1) * 4);
    int*            ghist   = (int*)           alloc16(GHN * 4);
    int*            part    = (int*)           alloc16(256 * 4);
    int2*           pairs   = (int2*)          alloc16((size_t)N_EDGES * 8);
    char*           big     =                  alloc16((size_t)N_NODES * HID * 2);  // 25.6MB >= E*8=12.8MB
    unsigned short* w1t     = (unsigned short*)alloc16(HID * F_IN * 2);
    unsigned short* w2t     = (unsigned short*)alloc16(F_OUT * HID * 2);

    int2*           spw     = (int2*)big;              // live: k_bscatter -> k_csr
    unsigned short* axh     = (unsigned short*)big;    // live: k_gather -> k_mlp

    const int GH_BLKS = (GHN + 255) / 256;   // 196

    k_pre<<<XB_BLKS + WC_BLKS + NCHB, 256, 0, stream>>>(x, xh, W1, W2, w1t, w2t, dst, ghist);
    k_scan_part<<<GH_BLKS, 256, 0, stream>>>(ghist, part, GHN);
    k_scan_top<<<1, 512, 0, stream>>>(part, GH_BLKS);
    k_scan_down<<<GH_BLKS, 256, 0, stream>>>(ghist, part, GHN);
    k_bscatter<<<NCHB, 256, 0, stream>>>(src, dst, ew, ghist, spw);
    k_csr<<<NBUCK, 512, 0, stream>>>(spw, ghist, row_ptr, dinv, pairs);
    k_gather<<<(N_NODES * 32 + 255) / 256, 256, 0, stream>>>(pairs, row_ptr, dinv, xh, axh);
    k_mlp<<<(N_NODES / 16 + 3) / 4, 256, 0, stream>>>(axh, w1t, b1, w2t, b2, out);
}